// Round 7
// baseline (106.892 us; speedup 1.0000x reference)
//
#include <hip/hip_runtime.h>
#include <hip/hip_fp16.h>

// SJLT projection: y[b, idx[d,j]] += sign[d,j] * x[b,d]; y *= 0.5
// B=4096, D=16384, P=1024, C=4.
//
// Gather formulation, fp16-staged, 8 rows/block, 512-thread blocks.
// Round-7: fix round-6 OOB (perm[2*PROJ_DIM-1-tid] -> perm[PROJ_DIM-1-tid]).
// Design: COUNT-SORTED column assignment.
//  - k_sort orders cols by total entry count; k_main slot A = perm[tid]
//    (ranks 0..511), slot B = perm[1023-tid] (ranks 1023..512). Lanes in a
//    wave have near-equal counts (exact trip counts, no wave-max waste),
//    rich+poor pairing equalizes per-wave totals.
//  - entry lists: single stride-32 array per (chunk,col), dummy-padded;
//    words 0..7 prefetched one chunk ahead into regs; words 8..15 (rare)
//    read directly from L2 (wave-coherent by sorting).
//  - fp16 granules [d][8 rows] 16 B, XOR-swizzled conflict-free staging
//    writes, 1 barrier/chunk, register prefetch of lists+x one chunk
//    ahead, full unroll for static ping-pong indexing.

#define BATCH     4096
#define ORIG_DIM  16384
#define PROJ_DIM  1024
#define NCHUNK    8
#define CHUNK_D   2048
#define ROWS      8
#define LCAP      32         // entries per (chunk,col) list (16 words)
#define NLISTS    (NCHUNK * PROJ_DIM)        // 8192
#define DUMMY_W   0x00020002u                // two e=2 entries (zero-flag)

// ws layout (bytes):
//   0      : int flag (1 if rand_indices is int64)
//   64     : int    cnt[NLISTS]              (32768 B)
//   32832  : ushort perm[PROJ_DIM]           (2048 B)
//   34880  : ushort entry[NLISTS*LCAP]       (524288 B)
#define WS_CNT_I   16
#define WS_PERM_B  32832
#define WS_ENT_B   34880
#define WS_NEEDED  (34880 + 524288)

typedef _Float16 h16x2 __attribute__((ext_vector_type(2)));

__global__ void k_init(const unsigned int* __restrict__ idx32,
                       int* __restrict__ ws_i,
                       uint4* __restrict__ ent4) {
    int t = blockIdx.x * 256 + threadIdx.x;        // 16384 threads
    ent4[2 * t]     = uint4{DUMMY_W, DUMMY_W, DUMMY_W, DUMMY_W};
    ent4[2 * t + 1] = uint4{DUMMY_W, DUMMY_W, DUMMY_W, DUMMY_W};
    if (t < NLISTS / 2)
        ((int2*)(ws_i + WS_CNT_I))[t] = int2{0, 0};
    if (blockIdx.x == 0 && threadIdx.x < 64) {
        unsigned int v = idx32[2 * threadIdx.x + 1];
        unsigned long long b = __ballot(v == 0u);
        if (threadIdx.x == 0) ws_i[0] = (b == 0xFFFFFFFFFFFFFFFFull) ? 1 : 0;
    }
}

__global__ void k_fill(const unsigned int* __restrict__ idx32,
                       const int* __restrict__ signs,
                       int* __restrict__ ws_i,
                       unsigned short* __restrict__ entry) {
    int t = blockIdx.x * 256 + threadIdx.x;        // 0..65535 == d*4 + j
    int flag64 = ws_i[0];
    unsigned int p = (flag64 ? idx32[2 * t] : idx32[t]) & (PROJ_DIM - 1);
    int d  = t >> 2;
    unsigned int sg = (signs[t] < 0) ? 1u : 0u;
    int chunk = d >> 11;
    int dl = d & (CHUNK_D - 1);
    unsigned int slot = (unsigned int)dl ^ (((unsigned int)dl >> 3) & 7u);
    unsigned short e = (unsigned short)((slot << 2) | sg);   // zero-flag = 0
    int base = chunk * PROJ_DIM + (int)p;
    int pos = atomicAdd(&ws_i[WS_CNT_I + base], 1);
    if (pos < LCAP)
        entry[(size_t)base * LCAP + pos] = e;
}

// counting-sort cols by total count (ascending); any within-bin order is fine
__global__ void k_sort(const int* __restrict__ cnt,
                       unsigned short* __restrict__ perm) {
    __shared__ int bins[256];
    __shared__ int base[256];
    int t = threadIdx.x;                 // 1024 threads
    if (t < 256) bins[t] = 0;
    __syncthreads();
    int tot = 0;
    #pragma unroll
    for (int ch = 0; ch < NCHUNK; ++ch) tot += cnt[ch * PROJ_DIM + t];
    tot = tot > 255 ? 255 : tot;
    int pos = atomicAdd(&bins[tot], 1);
    __syncthreads();
    if (t == 0) {
        int s = 0;
        for (int i = 0; i < 256; ++i) { base[i] = s; s += bins[i]; }
    }
    __syncthreads();
    perm[base[tot] + pos] = (unsigned short)t;
}

// process one entry E (8 rows via 4x v_pk_fma_f16) into ha0..ha3
#define PROC1(E) { \
    unsigned int _e = (unsigned int)(E); \
    uint4 _q = xsb[_e >> 2]; \
    unsigned int _s = (_e & 2u) ? 0u \
                    : ((_e & 1u) ? 0xBC00BC00u : 0x3C003C00u); \
    h16x2 _sp = __builtin_bit_cast(h16x2, _s); \
    ha0 = __builtin_elementwise_fma(__builtin_bit_cast(h16x2, _q.x), _sp, ha0); \
    ha1 = __builtin_elementwise_fma(__builtin_bit_cast(h16x2, _q.y), _sp, ha1); \
    ha2 = __builtin_elementwise_fma(__builtin_bit_cast(h16x2, _q.z), _sp, ha2); \
    ha3 = __builtin_elementwise_fma(__builtin_bit_cast(h16x2, _q.w), _sp, ha3); }

#define PROC2(W) { PROC1((W) & 0xffffu); PROC1((W) >> 16); }

// gather one slot: exact word-count wm from N, words 0..7 in H0/H1 regs,
// deep words 8..15 direct from L2 (rare, wave-coherent by sorting)
#define GSLOT(CH, COL, N, H0, H1, SLOT) { \
    h16x2 ha0{0,0}, ha1{0,0}, ha2{0,0}, ha3{0,0}; \
    int wm = ((N) + 1) >> 1; \
    if (wm > 0) { PROC2(H0.x); \
    if (wm > 1) { PROC2(H0.y); \
    if (wm > 2) { PROC2(H0.z); \
    if (wm > 3) { PROC2(H0.w); \
    if (wm > 4) { PROC2(H1.x); \
    if (wm > 5) { PROC2(H1.y); \
    if (wm > 6) { PROC2(H1.z); \
    if (wm > 7) { PROC2(H1.w); \
    if (wm > 8) { \
        const unsigned int* dp = (const unsigned int*) \
            (entry + ((size_t)((CH) * PROJ_DIM) + (COL)) * LCAP); \
        int we = wm < 16 ? wm : 16; \
        for (int w = 8; w < we; ++w) { unsigned int wd = dp[w]; PROC2(wd); } \
    }}}}}}}}} \
    accf[SLOT][0] += (float)ha0[0]; accf[SLOT][1] += (float)ha0[1]; \
    accf[SLOT][2] += (float)ha1[0]; accf[SLOT][3] += (float)ha1[1]; \
    accf[SLOT][4] += (float)ha2[0]; accf[SLOT][5] += (float)ha2[1]; \
    accf[SLOT][6] += (float)ha3[0]; accf[SLOT][7] += (float)ha3[1]; }

__launch_bounds__(512, 4)
__global__ void k_main(const float* __restrict__ x,
                       const int* __restrict__ cnt,
                       const unsigned short* __restrict__ perm,
                       const unsigned short* __restrict__ entry,
                       float* __restrict__ y) {
    __shared__ uint4 xs[2][CHUNK_D];     // 2 x 32 KiB, fp16 granules [d][8 rows]
    const int tid = threadIdx.x;         // 0..511
    const int b0  = blockIdx.x * ROWS;

    const float* xp = x + (size_t)b0 * ORIG_DIM + tid * 4;

    const int colA = perm[tid];                  // ranks 0..511 (poor)
    const int colB = perm[PROJ_DIM - 1 - tid];   // ranks 1023..512 (rich)

    uint4 hA0[2], hA1[2], hB0[2], hB1[2];
    int   nA[2], nB[2];
    float4 pv[ROWS];

    // ---- prologue: prefetch chunk-0 lists + counts, then chunk-0 x ----
    {
        const unsigned short* pa = entry + (size_t)colA * LCAP;
        const unsigned short* pb = entry + (size_t)colB * LCAP;
        hA0[0] = *(const uint4*)pa;  hA1[0] = *(const uint4*)(pa + 8);
        hB0[0] = *(const uint4*)pb;  hB1[0] = *(const uint4*)(pb + 8);
        nA[0] = cnt[colA];           nB[0] = cnt[colB];
    }
    #pragma unroll
    for (int r = 0; r < ROWS; ++r)
        pv[r] = *(const float4*)(xp + (size_t)r * ORIG_DIM);

    float accf[2][ROWS];
    #pragma unroll
    for (int k = 0; k < 2; ++k)
        #pragma unroll
        for (int r = 0; r < ROWS; ++r) accf[k][r] = 0.f;

    #pragma unroll
    for (int ch = 0; ch < NCHUNK; ++ch) {
        const int cur = ch & 1;
        uint4* xsb = xs[cur];

        // ---- pack 4 granules (fp16 RTZ) & ds_write_b128, swizzled ----
        #pragma unroll
        for (int i = 0; i < 4; ++i) {
            #define CMPV(R) (i == 0 ? pv[R].x : i == 1 ? pv[R].y : \
                             i == 2 ? pv[R].z : pv[R].w)
            uint4 w;
            w.x = __builtin_bit_cast(unsigned int, __builtin_amdgcn_cvt_pkrtz(CMPV(0), CMPV(1)));
            w.y = __builtin_bit_cast(unsigned int, __builtin_amdgcn_cvt_pkrtz(CMPV(2), CMPV(3)));
            w.z = __builtin_bit_cast(unsigned int, __builtin_amdgcn_cvt_pkrtz(CMPV(4), CMPV(5)));
            w.w = __builtin_bit_cast(unsigned int, __builtin_amdgcn_cvt_pkrtz(CMPV(6), CMPV(7)));
            #undef CMPV
            int dl = tid * 4 + i;
            int slot = dl ^ ((dl >> 3) & 7);
            xsb[slot] = w;
        }

        // ---- issue NEXT chunk's prefetches (lists+counts, then x) ----
        if (ch + 1 < NCHUNK) {
            const int nxt = (ch + 1) & 1;
            const size_t lb = (size_t)(ch + 1) * PROJ_DIM;
            const unsigned short* pa = entry + (lb + colA) * LCAP;
            const unsigned short* pb = entry + (lb + colB) * LCAP;
            hA0[nxt] = *(const uint4*)pa;  hA1[nxt] = *(const uint4*)(pa + 8);
            hB0[nxt] = *(const uint4*)pb;  hB1[nxt] = *(const uint4*)(pb + 8);
            nA[nxt] = cnt[lb + colA];      nB[nxt] = cnt[lb + colB];
            const float* xq = xp + (size_t)(ch + 1) * CHUNK_D;
            #pragma unroll
            for (int r = 0; r < ROWS; ++r)
                pv[r] = *(const float4*)(xq + (size_t)r * ORIG_DIM);
        }

        __syncthreads();

        // ---- gather both slots from registers, exact trip counts ----
        GSLOT(ch, colA, nA[cur], hA0[cur], hA1[cur], 0);
        GSLOT(ch, colB, nB[cur], hB0[cur], hB1[cur], 1);
    }

    // ---- epilogue: y = acc * 1/sqrt(4) (scattered by sorted col) ----
    float* ybA = y + (size_t)b0 * PROJ_DIM + colA;
    float* ybB = y + (size_t)b0 * PROJ_DIM + colB;
    #pragma unroll
    for (int r = 0; r < ROWS; ++r) {
        ybA[(size_t)r * PROJ_DIM] = accf[0][r] * 0.5f;
        ybB[(size_t)r * PROJ_DIM] = accf[1][r] * 0.5f;
    }
}

// Fallback if workspace is too small: per-row LDS atomic scatter.
__global__ void k_fallback(const float* __restrict__ x,
                           const unsigned int* __restrict__ idx32,
                           const int* __restrict__ signs,
                           float* __restrict__ y) {
    __shared__ float ys[PROJ_DIM];
    __shared__ int sflag;
    int tid = threadIdx.x;
    int b = blockIdx.x;
    if (tid < 64) {
        unsigned int v = idx32[2 * tid + 1];
        unsigned long long bl = __ballot(v == 0u);
        if (tid == 0) sflag = (bl == 0xFFFFFFFFFFFFFFFFull) ? 1 : 0;
    }
    for (int i = tid; i < PROJ_DIM; i += 256) ys[i] = 0.0f;
    __syncthreads();
    int f = sflag;
    const float* xr = x + (size_t)b * ORIG_DIM;
    for (int d = tid; d < ORIG_DIM; d += 256) {
        float v = xr[d];
        #pragma unroll
        for (int j = 0; j < 4; ++j) {
            int t = d * 4 + j;
            unsigned int p = (f ? idx32[2 * t] : idx32[t]) & (PROJ_DIM - 1);
            atomicAdd(&ys[p], (signs[t] < 0) ? -v : v);
        }
    }
    __syncthreads();
    for (int i = tid; i < PROJ_DIM; i += 256)
        y[(size_t)b * PROJ_DIM + i] = ys[i] * 0.5f;
}

extern "C" void kernel_launch(void* const* d_in, const int* in_sizes, int n_in,
                              void* d_out, int out_size, void* d_ws, size_t ws_size,
                              hipStream_t stream) {
    const float*        x     = (const float*)d_in[0];
    const unsigned int* idx32 = (const unsigned int*)d_in[1];
    const int*          signs = (const int*)d_in[2];
    float*              y     = (float*)d_out;

    if (ws_size >= (size_t)WS_NEEDED) {
        int* ws_i = (int*)d_ws;
        unsigned short* perm  = (unsigned short*)((char*)d_ws + WS_PERM_B);
        unsigned short* entry = (unsigned short*)((char*)d_ws + WS_ENT_B);
        k_init<<<64, 256, 0, stream>>>(idx32, ws_i, (uint4*)entry);
        k_fill<<<(ORIG_DIM * 4) / 256, 256, 0, stream>>>(idx32, signs, ws_i, entry);
        k_sort<<<1, 1024, 0, stream>>>(ws_i + WS_CNT_I, perm);
        k_main<<<BATCH / ROWS, 512, 0, stream>>>(x, ws_i + WS_CNT_I, perm, entry, y);
    } else {
        k_fallback<<<BATCH, 256, 0, stream>>>(x, idx32, signs, y);
    }
}

// Round 8
// 96.553 us; speedup vs baseline: 1.1071x; 1.1071x over previous
//
#include <hip/hip_runtime.h>
#include <hip/hip_fp16.h>

// SJLT projection: y[b, idx[d,j]] += sign[d,j] * x[b,d]; y *= 0.5
// B=4096, D=16384, P=1024, C=4.
//
// Gather formulation, fp16-staged, 8 rows/block, 1024-thread blocks,
// ONE column per thread (col = tid). Round-8 changes vs round 7:
//  - drop count-sort (serial k_sort cost ~15us, no k_main gain) and the
//    branchy exact-count gather; restore round-5 straight-line
//    dummy-padded head-12 + checked tail words (batched ds_reads).
//  - 1024-thr blocks, 1 col/thread: per-thread register state halves
//    (pv = 8 x float2, one list), __launch_bounds__(1024,8) forces
//    <=64 VGPR -> 32 waves/CU (2 blocks x 16 waves) vs 16 before.
//  - unified entry table, stride 32 entries (16 words): words 0..5 head
//    (12 entries), words 6..9 checked tail (entries 12..19), words
//    10..15 deep tail (entries 20..31, lazy cnt read, ~2.6% of waves).

#define BATCH     4096
#define ORIG_DIM  16384
#define PROJ_DIM  1024
#define NCHUNK    8
#define CHUNK_D   2048
#define ROWS      8
#define LCAP      32
#define NLISTS    (NCHUNK * PROJ_DIM)        // 8192
#define DUMMY_W   0x00020002u                // two e=2 entries (zero-flag)

// ws layout (bytes):
//   0      : int flag (1 if rand_indices is int64)
//   64     : int    cnt[NLISTS]              (32768 B)
//   32832  : ushort entry[NLISTS*LCAP]       (524288 B)
#define WS_CNT_I   16
#define WS_ENT_B   32832
#define WS_NEEDED  (32832 + 524288)

typedef _Float16 h16x2 __attribute__((ext_vector_type(2)));

__global__ void k_init(const unsigned int* __restrict__ idx32,
                       int* __restrict__ ws_i,
                       uint4* __restrict__ ent4) {
    int t = blockIdx.x * 256 + threadIdx.x;        // 16384 threads
    ent4[2 * t]     = uint4{DUMMY_W, DUMMY_W, DUMMY_W, DUMMY_W};
    ent4[2 * t + 1] = uint4{DUMMY_W, DUMMY_W, DUMMY_W, DUMMY_W};
    if (t < NLISTS / 2)
        ((int2*)(ws_i + WS_CNT_I))[t] = int2{0, 0};
    if (blockIdx.x == 0 && threadIdx.x < 64) {
        unsigned int v = idx32[2 * threadIdx.x + 1];
        unsigned long long b = __ballot(v == 0u);
        if (threadIdx.x == 0) ws_i[0] = (b == 0xFFFFFFFFFFFFFFFFull) ? 1 : 0;
    }
}

__global__ void k_fill(const unsigned int* __restrict__ idx32,
                       const int* __restrict__ signs,
                       int* __restrict__ ws_i,
                       unsigned short* __restrict__ entry) {
    int t = blockIdx.x * 256 + threadIdx.x;        // 0..65535 == d*4 + j
    int flag64 = ws_i[0];
    unsigned int p = (flag64 ? idx32[2 * t] : idx32[t]) & (PROJ_DIM - 1);
    int d  = t >> 2;
    unsigned int sg = (signs[t] < 0) ? 1u : 0u;
    int chunk = d >> 11;
    int dl = d & (CHUNK_D - 1);
    unsigned int slot = (unsigned int)dl ^ (((unsigned int)dl >> 3) & 7u);
    unsigned short e = (unsigned short)((slot << 2) | sg);   // zero-flag = 0
    int base = chunk * PROJ_DIM + (int)p;
    int pos = atomicAdd(&ws_i[WS_CNT_I + base], 1);
    if (pos < LCAP)
        entry[(size_t)base * LCAP + pos] = e;
}

// process one entry E (8 rows via 4x v_pk_fma_f16)
#define PROC1(E) { \
    unsigned int _e = (unsigned int)(E); \
    uint4 _q = xsb[_e >> 2]; \
    unsigned int _s = (_e & 2u) ? 0u \
                    : ((_e & 1u) ? 0xBC00BC00u : 0x3C003C00u); \
    h16x2 _sp = __builtin_bit_cast(h16x2, _s); \
    ha0 = __builtin_elementwise_fma(__builtin_bit_cast(h16x2, _q.x), _sp, ha0); \
    ha1 = __builtin_elementwise_fma(__builtin_bit_cast(h16x2, _q.y), _sp, ha1); \
    ha2 = __builtin_elementwise_fma(__builtin_bit_cast(h16x2, _q.z), _sp, ha2); \
    ha3 = __builtin_elementwise_fma(__builtin_bit_cast(h16x2, _q.w), _sp, ha3); }

#define PROC2(W) { PROC1((W) & 0xffffu); PROC1((W) >> 16); }

__launch_bounds__(1024, 8)
__global__ void k_main(const float* __restrict__ x,
                       const int* __restrict__ cnt,
                       const unsigned short* __restrict__ entry,
                       float* __restrict__ y) {
    __shared__ uint4 xs[2][CHUNK_D];     // 2 x 32 KiB, fp16 granules [d][8 rows]
    const int tid = threadIdx.x;         // 0..1023  == column
    const int b0  = blockIdx.x * ROWS;

    // this thread stages d-pair {2*tid, 2*tid+1} of each chunk
    const float* xp = x + (size_t)b0 * ORIG_DIM + tid * 2;

    uint4 pf_h0[2];      // head words 0..3  (entries 0..7)
    uint2 pf_h1[2];      // head words 4..5  (entries 8..11)
    uint4 pf_t [2];      // tail words 6..9  (entries 12..19)
    float2 pv[ROWS];

    // ---- prologue: prefetch chunk-0 list, then chunk-0 x ----
    {
        const unsigned short* lp = entry + (size_t)tid * LCAP;
        pf_h0[0] = *(const uint4*)lp;
        pf_h1[0] = *(const uint2*)(lp + 8);
        pf_t [0] = *(const uint4*)(lp + 12);
    }
    #pragma unroll
    for (int r = 0; r < ROWS; ++r)
        pv[r] = *(const float2*)(xp + (size_t)r * ORIG_DIM);

    float accf[ROWS];
    #pragma unroll
    for (int r = 0; r < ROWS; ++r) accf[r] = 0.f;

    #pragma unroll
    for (int ch = 0; ch < NCHUNK; ++ch) {
        const int cur = ch & 1;
        uint4* xsb = xs[cur];

        // ---- pack 2 granules (fp16 RTZ) & ds_write_b128, swizzled ----
        {
            int dl0 = tid * 2;
            int dl1 = dl0 + 1;
            uint4 w0, w1;
            w0.x = __builtin_bit_cast(unsigned int, __builtin_amdgcn_cvt_pkrtz(pv[0].x, pv[1].x));
            w0.y = __builtin_bit_cast(unsigned int, __builtin_amdgcn_cvt_pkrtz(pv[2].x, pv[3].x));
            w0.z = __builtin_bit_cast(unsigned int, __builtin_amdgcn_cvt_pkrtz(pv[4].x, pv[5].x));
            w0.w = __builtin_bit_cast(unsigned int, __builtin_amdgcn_cvt_pkrtz(pv[6].x, pv[7].x));
            w1.x = __builtin_bit_cast(unsigned int, __builtin_amdgcn_cvt_pkrtz(pv[0].y, pv[1].y));
            w1.y = __builtin_bit_cast(unsigned int, __builtin_amdgcn_cvt_pkrtz(pv[2].y, pv[3].y));
            w1.z = __builtin_bit_cast(unsigned int, __builtin_amdgcn_cvt_pkrtz(pv[4].y, pv[5].y));
            w1.w = __builtin_bit_cast(unsigned int, __builtin_amdgcn_cvt_pkrtz(pv[6].y, pv[7].y));
            xsb[dl0 ^ ((dl0 >> 3) & 7)] = w0;
            xsb[dl1 ^ ((dl1 >> 3) & 7)] = w1;
        }

        // ---- issue NEXT chunk's prefetches (list, then x) ----
        if (ch + 1 < NCHUNK) {
            const int nxt = (ch + 1) & 1;
            const unsigned short* lp =
                entry + ((size_t)(ch + 1) * PROJ_DIM + tid) * LCAP;
            pf_h0[nxt] = *(const uint4*)lp;
            pf_h1[nxt] = *(const uint2*)(lp + 8);
            pf_t [nxt] = *(const uint4*)(lp + 12);
            const float* xq = xp + (size_t)(ch + 1) * CHUNK_D;
            #pragma unroll
            for (int r = 0; r < ROWS; ++r)
                pv[r] = *(const float2*)(xq + (size_t)r * ORIG_DIM);
        }

        __syncthreads();

        // ---- gather from registers: straight-line head, checked tail ----
        h16x2 ha0{0,0}, ha1{0,0}, ha2{0,0}, ha3{0,0};
        {
            uint4 h0 = pf_h0[cur];
            uint2 h1 = pf_h1[cur];
            uint4 t  = pf_t [cur];
            PROC2(h0.x); PROC2(h0.y); PROC2(h0.z); PROC2(h0.w);
            PROC2(h1.x); PROC2(h1.y);
            if (t.x != DUMMY_W) { PROC2(t.x); }
            if (t.y != DUMMY_W) { PROC2(t.y); }
            if (t.z != DUMMY_W) { PROC2(t.z); }
            if (t.w != DUMMY_W) {            // n >= 19: rare deep tail (~2.6% of waves)
                PROC2(t.w);
                int base = ch * PROJ_DIM + tid;
                int n = cnt[base];
                int wm = (n + 1) >> 1;
                int we = wm < 16 ? wm : 16;
                const unsigned int* dp =
                    (const unsigned int*)(entry + (size_t)base * LCAP);
                for (int w = 10; w < we; ++w) { unsigned int wd = dp[w]; PROC2(wd); }
            }
        }

        // ---- flush fp16 pair-accumulators into fp32 ----
        accf[0] += (float)ha0[0]; accf[1] += (float)ha0[1];
        accf[2] += (float)ha1[0]; accf[3] += (float)ha1[1];
        accf[4] += (float)ha2[0]; accf[5] += (float)ha2[1];
        accf[6] += (float)ha3[0]; accf[7] += (float)ha3[1];
    }

    // ---- epilogue: y = acc * 1/sqrt(4), coalesced (col = tid) ----
    float* yb = y + (size_t)b0 * PROJ_DIM + tid;
    #pragma unroll
    for (int r = 0; r < ROWS; ++r)
        yb[(size_t)r * PROJ_DIM] = accf[r] * 0.5f;
}

// Fallback if workspace is too small: per-row LDS atomic scatter.
__global__ void k_fallback(const float* __restrict__ x,
                           const unsigned int* __restrict__ idx32,
                           const int* __restrict__ signs,
                           float* __restrict__ y) {
    __shared__ float ys[PROJ_DIM];
    __shared__ int sflag;
    int tid = threadIdx.x;
    int b = blockIdx.x;
    if (tid < 64) {
        unsigned int v = idx32[2 * tid + 1];
        unsigned long long bl = __ballot(v == 0u);
        if (tid == 0) sflag = (bl == 0xFFFFFFFFFFFFFFFFull) ? 1 : 0;
    }
    for (int i = tid; i < PROJ_DIM; i += 256) ys[i] = 0.0f;
    __syncthreads();
    int f = sflag;
    const float* xr = x + (size_t)b * ORIG_DIM;
    for (int d = tid; d < ORIG_DIM; d += 256) {
        float v = xr[d];
        #pragma unroll
        for (int j = 0; j < 4; ++j) {
            int t = d * 4 + j;
            unsigned int p = (f ? idx32[2 * t] : idx32[t]) & (PROJ_DIM - 1);
            atomicAdd(&ys[p], (signs[t] < 0) ? -v : v);
        }
    }
    __syncthreads();
    for (int i = tid; i < PROJ_DIM; i += 256)
        y[(size_t)b * PROJ_DIM + i] = ys[i] * 0.5f;
}

extern "C" void kernel_launch(void* const* d_in, const int* in_sizes, int n_in,
                              void* d_out, int out_size, void* d_ws, size_t ws_size,
                              hipStream_t stream) {
    const float*        x     = (const float*)d_in[0];
    const unsigned int* idx32 = (const unsigned int*)d_in[1];
    const int*          signs = (const int*)d_in[2];
    float*              y     = (float*)d_out;

    if (ws_size >= (size_t)WS_NEEDED) {
        int* ws_i = (int*)d_ws;
        unsigned short* entry = (unsigned short*)((char*)d_ws + WS_ENT_B);
        k_init<<<64, 256, 0, stream>>>(idx32, ws_i, (uint4*)entry);
        k_fill<<<(ORIG_DIM * 4) / 256, 256, 0, stream>>>(idx32, signs, ws_i, entry);
        k_main<<<BATCH / ROWS, 1024, 0, stream>>>(x, ws_i + WS_CNT_I, entry, y);
    } else {
        k_fallback<<<BATCH, 256, 0, stream>>>(x, idx32, signs, y);
    }
}

// Round 9
// 92.370 us; speedup vs baseline: 1.1572x; 1.0453x over previous
//
#include <hip/hip_runtime.h>
#include <hip/hip_fp16.h>

// SJLT projection: y[b, idx[d,j]] += sign[d,j] * x[b,d]; y *= 0.5
// B=4096, D=16384, P=1024, C=4.
//
// Gather formulation, fp16-staged, 8 rows/block, 1024-thread blocks,
// one column per thread. Round-9: register diet so the kernel REALLY fits
// 64 VGPR under __launch_bounds__(1024,8) -> 32 waves/CU without spills
// (round 8's regression = spill traffic from ~70 VGPR demand):
//  - tail prefetch shrunk to uint2 (entries 12..15), saving 4 VGPR;
//  - cnt prefetched (2 VGPR) and n>16 (0.37%/lane) handled by lazy exact
//    L2 reads of words 8..15;
//  - persistent state ~42 VGPR + transients -> ~56 total.
// Kept: fp16 granules [d][8 rows] (16 B), XOR-swizzled conflict-free
// staging writes, 1 barrier/chunk, register prefetch of lists+x one chunk
// ahead, full unroll for static ping-pong indexing.

#define BATCH     4096
#define ORIG_DIM  16384
#define PROJ_DIM  1024
#define NCHUNK    8
#define CHUNK_D   2048
#define ROWS      8
#define LCAP      32
#define NLISTS    (NCHUNK * PROJ_DIM)        // 8192
#define DUMMY_W   0x00020002u                // two e=2 entries (zero-flag)

// ws layout (bytes):
//   0      : int flag (1 if rand_indices is int64)
//   64     : int    cnt[NLISTS]              (32768 B)
//   32832  : ushort entry[NLISTS*LCAP]       (524288 B)
#define WS_CNT_I   16
#define WS_ENT_B   32832
#define WS_NEEDED  (32832 + 524288)

typedef _Float16 h16x2 __attribute__((ext_vector_type(2)));

__global__ void k_init(const unsigned int* __restrict__ idx32,
                       int* __restrict__ ws_i,
                       uint4* __restrict__ ent4) {
    int t = blockIdx.x * 256 + threadIdx.x;        // 16384 threads
    ent4[2 * t]     = uint4{DUMMY_W, DUMMY_W, DUMMY_W, DUMMY_W};
    ent4[2 * t + 1] = uint4{DUMMY_W, DUMMY_W, DUMMY_W, DUMMY_W};
    if (t < NLISTS / 2)
        ((int2*)(ws_i + WS_CNT_I))[t] = int2{0, 0};
    if (blockIdx.x == 0 && threadIdx.x < 64) {
        unsigned int v = idx32[2 * threadIdx.x + 1];
        unsigned long long b = __ballot(v == 0u);
        if (threadIdx.x == 0) ws_i[0] = (b == 0xFFFFFFFFFFFFFFFFull) ? 1 : 0;
    }
}

__global__ void k_fill(const unsigned int* __restrict__ idx32,
                       const int* __restrict__ signs,
                       int* __restrict__ ws_i,
                       unsigned short* __restrict__ entry) {
    int t = blockIdx.x * 256 + threadIdx.x;        // 0..65535 == d*4 + j
    int flag64 = ws_i[0];
    unsigned int p = (flag64 ? idx32[2 * t] : idx32[t]) & (PROJ_DIM - 1);
    int d  = t >> 2;
    unsigned int sg = (signs[t] < 0) ? 1u : 0u;
    int chunk = d >> 11;
    int dl = d & (CHUNK_D - 1);
    unsigned int slot = (unsigned int)dl ^ (((unsigned int)dl >> 3) & 7u);
    unsigned short e = (unsigned short)((slot << 2) | sg);   // zero-flag = 0
    int base = chunk * PROJ_DIM + (int)p;
    int pos = atomicAdd(&ws_i[WS_CNT_I + base], 1);
    if (pos < LCAP)
        entry[(size_t)base * LCAP + pos] = e;
}

// process one entry E (8 rows via 4x v_pk_fma_f16)
#define PROC1(E) { \
    unsigned int _e = (unsigned int)(E); \
    uint4 _q = xsb[_e >> 2]; \
    unsigned int _s = (_e & 2u) ? 0u \
                    : ((_e & 1u) ? 0xBC00BC00u : 0x3C003C00u); \
    h16x2 _sp = __builtin_bit_cast(h16x2, _s); \
    ha0 = __builtin_elementwise_fma(__builtin_bit_cast(h16x2, _q.x), _sp, ha0); \
    ha1 = __builtin_elementwise_fma(__builtin_bit_cast(h16x2, _q.y), _sp, ha1); \
    ha2 = __builtin_elementwise_fma(__builtin_bit_cast(h16x2, _q.z), _sp, ha2); \
    ha3 = __builtin_elementwise_fma(__builtin_bit_cast(h16x2, _q.w), _sp, ha3); }

#define PROC2(W) { PROC1((W) & 0xffffu); PROC1((W) >> 16); }

__launch_bounds__(1024, 8)
__global__ void k_main(const float* __restrict__ x,
                       const int* __restrict__ cnt,
                       const unsigned short* __restrict__ entry,
                       float* __restrict__ y) {
    __shared__ uint4 xs[2][CHUNK_D];     // 2 x 32 KiB, fp16 granules [d][8 rows]
    const int tid = threadIdx.x;         // 0..1023  == column
    const int b0  = blockIdx.x * ROWS;

    // this thread stages d-pair {2*tid, 2*tid+1} of each chunk
    const float* xp = x + (size_t)b0 * ORIG_DIM + tid * 2;

    uint4 pf_h0[2];      // head words 0..3  (entries 0..7)
    uint2 pf_h1[2];      // head words 4..5  (entries 8..11)
    uint2 pf_t [2];      // tail words 6..7  (entries 12..15)
    int   nn   [2];      // list count
    float2 pv[ROWS];

    // ---- prologue: prefetch chunk-0 list + count, then chunk-0 x ----
    {
        const unsigned short* lp = entry + (size_t)tid * LCAP;
        pf_h0[0] = *(const uint4*)lp;
        pf_h1[0] = *(const uint2*)(lp + 8);
        pf_t [0] = *(const uint2*)(lp + 12);
        nn   [0] = cnt[tid];
    }
    #pragma unroll
    for (int r = 0; r < ROWS; ++r)
        pv[r] = *(const float2*)(xp + (size_t)r * ORIG_DIM);

    float accf[ROWS];
    #pragma unroll
    for (int r = 0; r < ROWS; ++r) accf[r] = 0.f;

    #pragma unroll
    for (int ch = 0; ch < NCHUNK; ++ch) {
        const int cur = ch & 1;
        uint4* xsb = xs[cur];

        // ---- pack 2 granules (fp16 RTZ) & ds_write_b128, swizzled ----
        {
            int dl0 = tid * 2;
            int dl1 = dl0 + 1;
            uint4 w0, w1;
            w0.x = __builtin_bit_cast(unsigned int, __builtin_amdgcn_cvt_pkrtz(pv[0].x, pv[1].x));
            w0.y = __builtin_bit_cast(unsigned int, __builtin_amdgcn_cvt_pkrtz(pv[2].x, pv[3].x));
            w0.z = __builtin_bit_cast(unsigned int, __builtin_amdgcn_cvt_pkrtz(pv[4].x, pv[5].x));
            w0.w = __builtin_bit_cast(unsigned int, __builtin_amdgcn_cvt_pkrtz(pv[6].x, pv[7].x));
            w1.x = __builtin_bit_cast(unsigned int, __builtin_amdgcn_cvt_pkrtz(pv[0].y, pv[1].y));
            w1.y = __builtin_bit_cast(unsigned int, __builtin_amdgcn_cvt_pkrtz(pv[2].y, pv[3].y));
            w1.z = __builtin_bit_cast(unsigned int, __builtin_amdgcn_cvt_pkrtz(pv[4].y, pv[5].y));
            w1.w = __builtin_bit_cast(unsigned int, __builtin_amdgcn_cvt_pkrtz(pv[6].y, pv[7].y));
            xsb[dl0 ^ ((dl0 >> 3) & 7)] = w0;
            xsb[dl1 ^ ((dl1 >> 3) & 7)] = w1;
        }

        // ---- issue NEXT chunk's prefetches (list+count, then x) ----
        if (ch + 1 < NCHUNK) {
            const int nxt = (ch + 1) & 1;
            const int base = (ch + 1) * PROJ_DIM + tid;
            const unsigned short* lp = entry + (size_t)base * LCAP;
            pf_h0[nxt] = *(const uint4*)lp;
            pf_h1[nxt] = *(const uint2*)(lp + 8);
            pf_t [nxt] = *(const uint2*)(lp + 12);
            nn   [nxt] = cnt[base];
            const float* xq = xp + (size_t)(ch + 1) * CHUNK_D;
            #pragma unroll
            for (int r = 0; r < ROWS; ++r)
                pv[r] = *(const float2*)(xq + (size_t)r * ORIG_DIM);
        }

        __syncthreads();

        // ---- gather from registers: straight-line head, checked tail ----
        h16x2 ha0{0,0}, ha1{0,0}, ha2{0,0}, ha3{0,0};
        {
            uint4 h0 = pf_h0[cur];
            uint2 h1 = pf_h1[cur];
            uint2 t  = pf_t [cur];
            int   n  = nn   [cur];
            PROC2(h0.x); PROC2(h0.y); PROC2(h0.z); PROC2(h0.w);
            PROC2(h1.x); PROC2(h1.y);
            if (t.x != DUMMY_W) { PROC2(t.x); }
            if (t.y != DUMMY_W) { PROC2(t.y); }
            if (n > 16) {        // deep tail, 0.37%/lane: lazy exact L2 reads
                int wm = (n + 1) >> 1;
                int we = wm < 16 ? wm : 16;
                const unsigned int* dp = (const unsigned int*)
                    (entry + ((size_t)(ch * PROJ_DIM) + tid) * LCAP);
                for (int w = 8; w < we; ++w) { unsigned int wd = dp[w]; PROC2(wd); }
            }
        }

        // ---- flush fp16 pair-accumulators into fp32 ----
        accf[0] += (float)ha0[0]; accf[1] += (float)ha0[1];
        accf[2] += (float)ha1[0]; accf[3] += (float)ha1[1];
        accf[4] += (float)ha2[0]; accf[5] += (float)ha2[1];
        accf[6] += (float)ha3[0]; accf[7] += (float)ha3[1];
    }

    // ---- epilogue: y = acc * 1/sqrt(4), coalesced (col = tid) ----
    float* yb = y + (size_t)b0 * PROJ_DIM + tid;
    #pragma unroll
    for (int r = 0; r < ROWS; ++r)
        yb[(size_t)r * PROJ_DIM] = accf[r] * 0.5f;
}

// Fallback if workspace is too small: per-row LDS atomic scatter.
__global__ void k_fallback(const float* __restrict__ x,
                           const unsigned int* __restrict__ idx32,
                           const int* __restrict__ signs,
                           float* __restrict__ y) {
    __shared__ float ys[PROJ_DIM];
    __shared__ int sflag;
    int tid = threadIdx.x;
    int b = blockIdx.x;
    if (tid < 64) {
        unsigned int v = idx32[2 * tid + 1];
        unsigned long long bl = __ballot(v == 0u);
        if (tid == 0) sflag = (bl == 0xFFFFFFFFFFFFFFFFull) ? 1 : 0;
    }
    for (int i = tid; i < PROJ_DIM; i += 256) ys[i] = 0.0f;
    __syncthreads();
    int f = sflag;
    const float* xr = x + (size_t)b * ORIG_DIM;
    for (int d = tid; d < ORIG_DIM; d += 256) {
        float v = xr[d];
        #pragma unroll
        for (int j = 0; j < 4; ++j) {
            int t = d * 4 + j;
            unsigned int p = (f ? idx32[2 * t] : idx32[t]) & (PROJ_DIM - 1);
            atomicAdd(&ys[p], (signs[t] < 0) ? -v : v);
        }
    }
    __syncthreads();
    for (int i = tid; i < PROJ_DIM; i += 256)
        y[(size_t)b * PROJ_DIM + i] = ys[i] * 0.5f;
}

extern "C" void kernel_launch(void* const* d_in, const int* in_sizes, int n_in,
                              void* d_out, int out_size, void* d_ws, size_t ws_size,
                              hipStream_t stream) {
    const float*        x     = (const float*)d_in[0];
    const unsigned int* idx32 = (const unsigned int*)d_in[1];
    const int*          signs = (const int*)d_in[2];
    float*              y     = (float*)d_out;

    if (ws_size >= (size_t)WS_NEEDED) {
        int* ws_i = (int*)d_ws;
        unsigned short* entry = (unsigned short*)((char*)d_ws + WS_ENT_B);
        k_init<<<64, 256, 0, stream>>>(idx32, ws_i, (uint4*)entry);
        k_fill<<<(ORIG_DIM * 4) / 256, 256, 0, stream>>>(idx32, signs, ws_i, entry);
        k_main<<<BATCH / ROWS, 1024, 0, stream>>>(x, ws_i + WS_CNT_I, entry, y);
    } else {
        k_fallback<<<BATCH, 256, 0, stream>>>(x, idx32, signs, y);
    }
}

// Round 10
// 83.006 us; speedup vs baseline: 1.2878x; 1.1128x over previous
//
#include <hip/hip_runtime.h>
#include <hip/hip_fp16.h>

// SJLT projection: y[b, idx[d,j]] += sign[d,j] * x[b,d]; y *= 0.5
// B=4096, D=16384, P=1024, C=4.
//
// Gather formulation, fp16-staged, 8 rows/block, 1024-thread blocks,
// one column per thread. Round-10: DEPTH-2 x prefetch.
//  - r5/r9 stalled each chunk at PACK: pv loads issued one gather-phase
//    (~500cy) earlier vs ~900cy cold-HBM latency. Now x(ch+2) is issued
//    into the pv buffer freed by PACK(ch): wait window = 2 gather phases,
//    compiler emits counted vmcnt (12 pending), queue never drains.
//  - __launch_bounds__(1024,4): VGPR cap 128, demand ~80 -> NO spill
//    (r8/r9 lesson: demanding 64 forced spills). 16 waves/CU (LDS-capped,
//    same as r5) -- this round isolates prefetch depth, not occupancy.
//  - unchanged: fp16 granules [d][8 rows] (16 B), XOR-swizzled
//    conflict-free staging writes, 1 barrier/chunk, list prefetch one
//    chunk ahead, unified stride-32 dummy-padded entry table,
//    straight-line head-12 + checked words 6..7 + lazy deep tail (n>16).

#define BATCH     4096
#define ORIG_DIM  16384
#define PROJ_DIM  1024
#define NCHUNK    8
#define CHUNK_D   2048
#define ROWS      8
#define LCAP      32
#define NLISTS    (NCHUNK * PROJ_DIM)        // 8192
#define DUMMY_W   0x00020002u                // two e=2 entries (zero-flag)

// ws layout (bytes):
//   0      : int flag (1 if rand_indices is int64)
//   64     : int    cnt[NLISTS]              (32768 B)
//   32832  : ushort entry[NLISTS*LCAP]       (524288 B)
#define WS_CNT_I   16
#define WS_ENT_B   32832
#define WS_NEEDED  (32832 + 524288)

typedef _Float16 h16x2 __attribute__((ext_vector_type(2)));

__global__ void k_init(const unsigned int* __restrict__ idx32,
                       int* __restrict__ ws_i,
                       uint4* __restrict__ ent4) {
    int t = blockIdx.x * 256 + threadIdx.x;        // 16384 threads
    ent4[2 * t]     = uint4{DUMMY_W, DUMMY_W, DUMMY_W, DUMMY_W};
    ent4[2 * t + 1] = uint4{DUMMY_W, DUMMY_W, DUMMY_W, DUMMY_W};
    if (t < NLISTS / 2)
        ((int2*)(ws_i + WS_CNT_I))[t] = int2{0, 0};
    if (blockIdx.x == 0 && threadIdx.x < 64) {
        unsigned int v = idx32[2 * threadIdx.x + 1];
        unsigned long long b = __ballot(v == 0u);
        if (threadIdx.x == 0) ws_i[0] = (b == 0xFFFFFFFFFFFFFFFFull) ? 1 : 0;
    }
}

__global__ void k_fill(const unsigned int* __restrict__ idx32,
                       const int* __restrict__ signs,
                       int* __restrict__ ws_i,
                       unsigned short* __restrict__ entry) {
    int t = blockIdx.x * 256 + threadIdx.x;        // 0..65535 == d*4 + j
    int flag64 = ws_i[0];
    unsigned int p = (flag64 ? idx32[2 * t] : idx32[t]) & (PROJ_DIM - 1);
    int d  = t >> 2;
    unsigned int sg = (signs[t] < 0) ? 1u : 0u;
    int chunk = d >> 11;
    int dl = d & (CHUNK_D - 1);
    unsigned int slot = (unsigned int)dl ^ (((unsigned int)dl >> 3) & 7u);
    unsigned short e = (unsigned short)((slot << 2) | sg);   // zero-flag = 0
    int base = chunk * PROJ_DIM + (int)p;
    int pos = atomicAdd(&ws_i[WS_CNT_I + base], 1);
    if (pos < LCAP)
        entry[(size_t)base * LCAP + pos] = e;
}

// process one entry E (8 rows via 4x v_pk_fma_f16)
#define PROC1(E) { \
    unsigned int _e = (unsigned int)(E); \
    uint4 _q = xsb[_e >> 2]; \
    unsigned int _s = (_e & 2u) ? 0u \
                    : ((_e & 1u) ? 0xBC00BC00u : 0x3C003C00u); \
    h16x2 _sp = __builtin_bit_cast(h16x2, _s); \
    ha0 = __builtin_elementwise_fma(__builtin_bit_cast(h16x2, _q.x), _sp, ha0); \
    ha1 = __builtin_elementwise_fma(__builtin_bit_cast(h16x2, _q.y), _sp, ha1); \
    ha2 = __builtin_elementwise_fma(__builtin_bit_cast(h16x2, _q.z), _sp, ha2); \
    ha3 = __builtin_elementwise_fma(__builtin_bit_cast(h16x2, _q.w), _sp, ha3); }

#define PROC2(W) { PROC1((W) & 0xffffu); PROC1((W) >> 16); }

__launch_bounds__(1024, 4)
__global__ void k_main(const float* __restrict__ x,
                       const int* __restrict__ cnt,
                       const unsigned short* __restrict__ entry,
                       float* __restrict__ y) {
    __shared__ uint4 xs[2][CHUNK_D];     // 2 x 32 KiB, fp16 granules [d][8 rows]
    const int tid = threadIdx.x;         // 0..1023  == column
    const int b0  = blockIdx.x * ROWS;

    // this thread stages d-pair {2*tid, 2*tid+1} of each chunk
    const float* xp = x + (size_t)b0 * ORIG_DIM + tid * 2;

    uint4 pf_h0[2];      // head words 0..3  (entries 0..7)
    uint2 pf_h1[2];      // head words 4..5  (entries 8..11)
    uint2 pf_t [2];      // tail words 6..7  (entries 12..15)
    int   nn   [2];      // list count
    float2 pv[2][ROWS];  // DEPTH-2 x prefetch (ping-pong by chunk parity)

    // ---- prologue: lists(ch0), x(ch0) -> pv[0], x(ch1) -> pv[1] ----
    {
        const unsigned short* lp = entry + (size_t)tid * LCAP;
        pf_h0[0] = *(const uint4*)lp;
        pf_h1[0] = *(const uint2*)(lp + 8);
        pf_t [0] = *(const uint2*)(lp + 12);
        nn   [0] = cnt[tid];
    }
    #pragma unroll
    for (int r = 0; r < ROWS; ++r)
        pv[0][r] = *(const float2*)(xp + (size_t)r * ORIG_DIM);
    #pragma unroll
    for (int r = 0; r < ROWS; ++r)
        pv[1][r] = *(const float2*)(xp + CHUNK_D + (size_t)r * ORIG_DIM);

    float accf[ROWS];
    #pragma unroll
    for (int r = 0; r < ROWS; ++r) accf[r] = 0.f;

    #pragma unroll
    for (int ch = 0; ch < NCHUNK; ++ch) {
        const int cur = ch & 1;
        uint4* xsb = xs[cur];

        // ---- pack 2 granules (fp16 RTZ) & ds_write_b128, swizzled ----
        // waits pv[cur] (issued 2 chunks ago -> ~2 gather phases coverage)
        {
            int dl0 = tid * 2;
            int dl1 = dl0 + 1;
            uint4 w0, w1;
            w0.x = __builtin_bit_cast(unsigned int, __builtin_amdgcn_cvt_pkrtz(pv[cur][0].x, pv[cur][1].x));
            w0.y = __builtin_bit_cast(unsigned int, __builtin_amdgcn_cvt_pkrtz(pv[cur][2].x, pv[cur][3].x));
            w0.z = __builtin_bit_cast(unsigned int, __builtin_amdgcn_cvt_pkrtz(pv[cur][4].x, pv[cur][5].x));
            w0.w = __builtin_bit_cast(unsigned int, __builtin_amdgcn_cvt_pkrtz(pv[cur][6].x, pv[cur][7].x));
            w1.x = __builtin_bit_cast(unsigned int, __builtin_amdgcn_cvt_pkrtz(pv[cur][0].y, pv[cur][1].y));
            w1.y = __builtin_bit_cast(unsigned int, __builtin_amdgcn_cvt_pkrtz(pv[cur][2].y, pv[cur][3].y));
            w1.z = __builtin_bit_cast(unsigned int, __builtin_amdgcn_cvt_pkrtz(pv[cur][4].y, pv[cur][5].y));
            w1.w = __builtin_bit_cast(unsigned int, __builtin_amdgcn_cvt_pkrtz(pv[cur][6].y, pv[cur][7].y));
            xsb[dl0 ^ ((dl0 >> 3) & 7)] = w0;
            xsb[dl1 ^ ((dl1 >> 3) & 7)] = w1;
        }

        // ---- issue prefetches: lists(ch+1), x(ch+2) into freed pv[cur] ----
        if (ch + 1 < NCHUNK) {
            const int nxt = (ch + 1) & 1;
            const int base = (ch + 1) * PROJ_DIM + tid;
            const unsigned short* lp = entry + (size_t)base * LCAP;
            pf_h0[nxt] = *(const uint4*)lp;
            pf_h1[nxt] = *(const uint2*)(lp + 8);
            pf_t [nxt] = *(const uint2*)(lp + 12);
            nn   [nxt] = cnt[base];
        }
        if (ch + 2 < NCHUNK) {
            const float* xq = xp + (size_t)(ch + 2) * CHUNK_D;
            #pragma unroll
            for (int r = 0; r < ROWS; ++r)
                pv[cur][r] = *(const float2*)(xq + (size_t)r * ORIG_DIM);
        }

        __syncthreads();

        // ---- gather from registers: straight-line head, checked tail ----
        h16x2 ha0{0,0}, ha1{0,0}, ha2{0,0}, ha3{0,0};
        {
            uint4 h0 = pf_h0[cur];
            uint2 h1 = pf_h1[cur];
            uint2 t  = pf_t [cur];
            int   n  = nn   [cur];
            PROC2(h0.x); PROC2(h0.y); PROC2(h0.z); PROC2(h0.w);
            PROC2(h1.x); PROC2(h1.y);
            if (t.x != DUMMY_W) { PROC2(t.x); }
            if (t.y != DUMMY_W) { PROC2(t.y); }
            if (n > 16) {        // deep tail, 0.37%/lane: lazy exact L2 reads
                int wm = (n + 1) >> 1;
                int we = wm < 16 ? wm : 16;
                const unsigned int* dp = (const unsigned int*)
                    (entry + ((size_t)(ch * PROJ_DIM) + tid) * LCAP);
                for (int w = 8; w < we; ++w) { unsigned int wd = dp[w]; PROC2(wd); }
            }
        }

        // ---- flush fp16 pair-accumulators into fp32 ----
        accf[0] += (float)ha0[0]; accf[1] += (float)ha0[1];
        accf[2] += (float)ha1[0]; accf[3] += (float)ha1[1];
        accf[4] += (float)ha2[0]; accf[5] += (float)ha2[1];
        accf[6] += (float)ha3[0]; accf[7] += (float)ha3[1];
    }

    // ---- epilogue: y = acc * 1/sqrt(4), coalesced (col = tid) ----
    float* yb = y + (size_t)b0 * PROJ_DIM + tid;
    #pragma unroll
    for (int r = 0; r < ROWS; ++r)
        yb[(size_t)r * PROJ_DIM] = accf[r] * 0.5f;
}

// Fallback if workspace is too small: per-row LDS atomic scatter.
__global__ void k_fallback(const float* __restrict__ x,
                           const unsigned int* __restrict__ idx32,
                           const int* __restrict__ signs,
                           float* __restrict__ y) {
    __shared__ float ys[PROJ_DIM];
    __shared__ int sflag;
    int tid = threadIdx.x;
    int b = blockIdx.x;
    if (tid < 64) {
        unsigned int v = idx32[2 * tid + 1];
        unsigned long long bl = __ballot(v == 0u);
        if (tid == 0) sflag = (bl == 0xFFFFFFFFFFFFFFFFull) ? 1 : 0;
    }
    for (int i = tid; i < PROJ_DIM; i += 256) ys[i] = 0.0f;
    __syncthreads();
    int f = sflag;
    const float* xr = x + (size_t)b * ORIG_DIM;
    for (int d = tid; d < ORIG_DIM; d += 256) {
        float v = xr[d];
        #pragma unroll
        for (int j = 0; j < 4; ++j) {
            int t = d * 4 + j;
            unsigned int p = (f ? idx32[2 * t] : idx32[t]) & (PROJ_DIM - 1);
            atomicAdd(&ys[p], (signs[t] < 0) ? -v : v);
        }
    }
    __syncthreads();
    for (int i = tid; i < PROJ_DIM; i += 256)
        y[(size_t)b * PROJ_DIM + i] = ys[i] * 0.5f;
}

extern "C" void kernel_launch(void* const* d_in, const int* in_sizes, int n_in,
                              void* d_out, int out_size, void* d_ws, size_t ws_size,
                              hipStream_t stream) {
    const float*        x     = (const float*)d_in[0];
    const unsigned int* idx32 = (const unsigned int*)d_in[1];
    const int*          signs = (const int*)d_in[2];
    float*              y     = (float*)d_out;

    if (ws_size >= (size_t)WS_NEEDED) {
        int* ws_i = (int*)d_ws;
        unsigned short* entry = (unsigned short*)((char*)d_ws + WS_ENT_B);
        k_init<<<64, 256, 0, stream>>>(idx32, ws_i, (uint4*)entry);
        k_fill<<<(ORIG_DIM * 4) / 256, 256, 0, stream>>>(idx32, signs, ws_i, entry);
        k_main<<<BATCH / ROWS, 1024, 0, stream>>>(x, ws_i + WS_CNT_I, entry, y);
    } else {
        k_fallback<<<BATCH, 256, 0, stream>>>(x, idx32, signs, y);
    }
}